// Round 9
// baseline (151.892 us; speedup 1.0000x reference)
//
#include <hip/hip_runtime.h>
#include <hip/hip_bf16.h>
#include <float.h>

// GraphSAGE: masked-max agg + ReLU + concat + Linear(256->128).
// B=4, N=512, C=128, OUT=128.
//
// R9: SINGLE dispatch, "last block does the GEMM" — no spinning anywhere.
//  - 2048 blocks, one node each (R7 agg: 4 waves, quarter-row, 8-wide padded
//    gather rounds). Write bf16 comb row -> __threadfence (release) ->
//    one atomicAdd(&cnt[node>>4], 1).
//  - The 16th finisher of each 16-node m-tile (old == base+15) continues:
//    __threadfence (acquire), then computes out[mt*16..+16][0..128) with
//    MFMA 16x16x32 (4 waves x 2 n-tiles, A-frags shared across the nt pair,
//    B-frags from L2-hot fp32 W).
//  R8 lesson: spin-polling starved the producers' release atomics (62us idle
//  kernel). Here every block runs to completion; 2048 RMWs total, zero waits.
//  Winner base hedged for both 0xAA poison and zero-init ws.

#define Bsz 4
#define Nn  512
#define Cc  128
#define OUTn 128
#define NNODES (Bsz * Nn)   // 2048
#define KK (2 * Cc)         // 256
#define POISON 0xAAAAAAAAu

typedef __bf16 bf16x8 __attribute__((ext_vector_type(8)));
typedef float  f32x4  __attribute__((ext_vector_type(4)));

static __device__ __forceinline__ unsigned short f2bf(float x) {
    __hip_bfloat16 h = __float2bfloat16(x);
    return *reinterpret_cast<unsigned short*>(&h);
}
static __device__ __forceinline__ __bf16 f2bf16(float x) {
    unsigned short u = f2bf(x);
    return *reinterpret_cast<__bf16*>(&u);
}

__global__ __launch_bounds__(256) void sage_lastblock(
    const float* __restrict__ adj,
    const float* __restrict__ feat,
    const float* __restrict__ W,          // fp32 [256][128]
    const float* __restrict__ bias,
    unsigned short* __restrict__ comb,    // ws: bf16 [2048][256]
    unsigned int* __restrict__ cnt,       // ws: [128] completion counters
    float* __restrict__ out)              // fp32 [2048][128]
{
    const int node = blockIdx.x;
    const int w = threadIdx.x >> 6;
    const int l = threadIdx.x & 63;
    const int b = node >> 9;
    const int i = node & (Nn - 1);
    const int mt = node >> 4;

    __shared__ unsigned short nbr[4][128];
    __shared__ float2 pmax[4][64];
    __shared__ int s_win;

    // ---- aggregation: wave w scans neighbor quarter [128w, 128w+128) ----
    const float* adjrow = adj + (size_t)node * Nn;
    const float2* f2 = (const float2*)(feat + (size_t)b * Nn * Cc);

    int c = 0;
    #pragma unroll
    for (int ch = 0; ch < 2; ++ch) {
        int j = w * 128 + ch * 64 + l;
        float a = adjrow[j];
        unsigned long long mask = __ballot(a > 0.0f);
        int pos = __popcll(mask & ((1ull << l) - 1ull));
        if (a > 0.0f) nbr[w][c + pos] = (unsigned short)j;
        c += __popcll(mask);
    }
    // Pad list to a multiple of 8 with a duplicate (max is idempotent).
    if (c > 0) {
        unsigned short p0 = nbr[w][0];
        int padded = (c + 7) & ~7;
        if (l < padded - c) nbr[w][c + l] = p0;
        c = padded;
    }

    float m0 = -FLT_MAX, m1 = -FLT_MAX;
    for (int k = 0; k < c; k += 8) {
        int j0 = nbr[w][k + 0], j1 = nbr[w][k + 1];
        int j2 = nbr[w][k + 2], j3 = nbr[w][k + 3];
        int j4 = nbr[w][k + 4], j5 = nbr[w][k + 5];
        int j6 = nbr[w][k + 6], j7 = nbr[w][k + 7];
        float2 v0 = f2[j0 * 64 + l];
        float2 v1 = f2[j1 * 64 + l];
        float2 v2 = f2[j2 * 64 + l];
        float2 v3 = f2[j3 * 64 + l];
        float2 v4 = f2[j4 * 64 + l];
        float2 v5 = f2[j5 * 64 + l];
        float2 v6 = f2[j6 * 64 + l];
        float2 v7 = f2[j7 * 64 + l];
        m0 = fmaxf(m0, fmaxf(fmaxf(fmaxf(v0.x, v1.x), fmaxf(v2.x, v3.x)),
                             fmaxf(fmaxf(v4.x, v5.x), fmaxf(v6.x, v7.x))));
        m1 = fmaxf(m1, fmaxf(fmaxf(fmaxf(v0.y, v1.y), fmaxf(v2.y, v3.y)),
                             fmaxf(fmaxf(v4.y, v5.y), fmaxf(v6.y, v7.y))));
    }
    pmax[w][l] = make_float2(m0, m1);
    __syncthreads();

    // Wave 0: combine partials, relu, self, store comb row; release + count.
    if (w == 0) {
        float2 p0 = pmax[0][l], p1 = pmax[1][l], p2 = pmax[2][l], p3 = pmax[3][l];
        float n0 = fmaxf(fmaxf(p0.x, p1.x), fmaxf(p2.x, p3.x));
        float n1 = fmaxf(fmaxf(p0.y, p1.y), fmaxf(p2.y, p3.y));
        // relu(max) maps no-neighbor (-FLT_MAX) to 0, matching the reference
        // (finfo.min is finite; its isfinite-guard never fires).
        n0 = fmaxf(n0, 0.0f);
        n1 = fmaxf(n1, 0.0f);
        float2 s = f2[i * 64 + l];

        ushort2* crow = (ushort2*)(comb + (size_t)node * KK);
        ushort2 sv; sv.x = f2bf(s.x); sv.y = f2bf(s.y);
        ushort2 nv; nv.x = f2bf(n0);  nv.y = f2bf(n1);
        crow[l]      = sv;   // self  ch [2l, 2l+1]
        crow[64 + l] = nv;   // neigh ch [128+2l, 128+2l+1]

        __threadfence();     // release: comb row visible device-wide
        if (l == 0) {
            unsigned int old = atomicAdd(&cnt[mt], 1u);
            // 16th finisher wins. Hedge base: documented 0xAA poison or zero.
            s_win = (old == POISON + 15u) || (old == 15u) ? 1 : 0;
        }
    }
    __syncthreads();
    if (!s_win) return;

    __threadfence();         // acquire: see the other 15 comb rows

    // ---- winner: GEMM for m-tile mt. Wave w -> n-tiles {2w, 2w+1}. ----
    // A-frag: lane holds A[m=frow][k=koff+j], 16B b128 from comb (shared
    // across both nt). B-frag from fp32 W (L2-hot), strided dword + cvt.
    // C/D: col = lane&15, row = (lane>>4)*4 + reg  [measured m89/m91]
    const int frow = l & 15;
    const int koff = (l >> 4) * 8;
    const int nt0 = w * 2, nt1 = w * 2 + 1;

    const __bf16* pa = (const __bf16*)comb + (size_t)(mt * 16 + frow) * KK + koff;
    const float*  wp0 = W + nt0 * 16 + frow;
    const float*  wp1 = W + nt1 * 16 + frow;

    f32x4 acc0 = {0.f, 0.f, 0.f, 0.f};
    f32x4 acc1 = {0.f, 0.f, 0.f, 0.f};
    #pragma unroll
    for (int ks = 0; ks < KK / 32; ++ks) {
        bf16x8 af = *(const bf16x8*)(pa + ks * 32);
        bf16x8 b0, b1;
        #pragma unroll
        for (int j = 0; j < 8; ++j) {
            size_t row = (size_t)(ks * 32 + koff + j) * OUTn;
            b0[j] = f2bf16(wp0[row]);
            b1[j] = f2bf16(wp1[row]);
        }
        acc0 = __builtin_amdgcn_mfma_f32_16x16x32_bf16(af, b0, acc0, 0, 0, 0);
        acc1 = __builtin_amdgcn_mfma_f32_16x16x32_bf16(af, b1, acc1, 0, 0, 0);
    }

    const int col = l & 15;
    const int r0  = (l >> 4) * 4;
    const float bv0 = bias[nt0 * 16 + col];
    const float bv1 = bias[nt1 * 16 + col];
    #pragma unroll
    for (int r = 0; r < 4; ++r) {
        size_t rowbase = (size_t)(mt * 16 + r0 + r) * OUTn;
        out[rowbase + nt0 * 16 + col] = acc0[r] + bv0;
        out[rowbase + nt1 * 16 + col] = acc1[r] + bv1;
    }
}

extern "C" void kernel_launch(void* const* d_in, const int* in_sizes, int n_in,
                              void* d_out, int out_size, void* d_ws, size_t ws_size,
                              hipStream_t stream) {
    const float* adj  = (const float*)d_in[0];
    const float* feat = (const float*)d_in[1];
    const float* W    = (const float*)d_in[2];
    const float* bias = (const float*)d_in[3];
    float* out = (float*)d_out;

    unsigned short* comb = (unsigned short*)d_ws;                        // 1 MB
    unsigned int*   cnt  = (unsigned int*)(comb + (size_t)NNODES * KK);  // 512 B

    sage_lastblock<<<dim3(NNODES), dim3(256), 0, stream>>>(
        adj, feat, W, bias, comb, cnt, out);
}

// Round 10
// 67.122 us; speedup vs baseline: 2.2629x; 2.2629x over previous
//
#include <hip/hip_runtime.h>
#include <hip/hip_bf16.h>
#include <float.h>

// GraphSAGE: masked-max agg + ReLU + concat + Linear(256->128).
// B=4, N=512, C=128, OUT=128.
//
// R10: SINGLE dispatch, ZERO inter-block sync (R8/R9 lesson: device-scope
// fences/atomics invalidate per-XCD L2 -> 25-50us losses; never again).
// Grid = 256 blocks = (mt 0..127) x (row-half 0..1); block = 1024 thr = 16
// waves, fully self-sufficient for its 8 output rows:
//   phase A: wave w -> node slot w&7, adjacency half w>>3. Ballot-compact
//            ~26 nbrs, pad to x8 (dup; max idempotent), 8-wide gather rounds
//            (~4 serial rounds only). Partial maxima -> LDS.
//   phase B: waves 0-7 combine halves, relu, + self row -> bf16 A-tile in
//            LDS (rows 8-15 zero). Wave w = n-tile w: MFMA 16x16x32, B-frag
//            from L2-hot fp32 W (R4/R7-proven), bias, store 8 valid rows.
// vs R5's failed fusion: 16 (not 8) waves/CU, 4 (not 13) serial gather
// rounds/wave, all 128 out cols per block. No ws, no fences, one dispatch.

#define Bsz 4
#define Nn  512
#define Cc  128
#define OUTn 128
#define NNODES (Bsz * Nn)   // 2048
#define KK (2 * Cc)         // 256
#define ROWP 264            // LDS A-tile row stride (bf16): +8 -> 4-bank skew

typedef __bf16 bf16x8 __attribute__((ext_vector_type(8)));
typedef float  f32x4  __attribute__((ext_vector_type(4)));

static __device__ __forceinline__ unsigned short f2bf(float x) {
    __hip_bfloat16 h = __float2bfloat16(x);
    return *reinterpret_cast<unsigned short*>(&h);
}
static __device__ __forceinline__ __bf16 f2bf16(float x) {
    unsigned short u = f2bf(x);
    return *reinterpret_cast<__bf16*>(&u);
}

__global__ __launch_bounds__(1024) void sage_fused(
    const float* __restrict__ adj,
    const float* __restrict__ feat,
    const float* __restrict__ W,      // fp32 [256][128]
    const float* __restrict__ bias,   // fp32 [128]
    float* __restrict__ out)          // fp32 [2048][128]
{
    const int bid = blockIdx.x;       // 0..255
    const int mt  = bid >> 1;         // 16-row m-tile
    const int rh  = bid & 1;          // which 8 rows of the tile
    const int w = threadIdx.x >> 6;   // 0..15
    const int l = threadIdx.x & 63;

    __shared__ unsigned short nbr[16][256];  // per-wave compacted half-row
    __shared__ float2 pm[16][64];            // per-wave partial maxima
    __shared__ unsigned short sA[16][ROWP];  // bf16 A-tile (rows 8..15 = 0)

    const int slot = w & 7;                  // node slot within the 8 rows
    const int half = w >> 3;                 // adjacency half [256h, 256h+256)
    const int node = mt * 16 + rh * 8 + slot;
    const int b = node >> 9;
    const int i = node & (Nn - 1);

    // ---- phase A: ballot-compact + 8-wide max-gather of half a row ----
    const float* adjrow = adj + (size_t)node * Nn;
    const float2* f2 = (const float2*)(feat + (size_t)b * Nn * Cc);

    int cnt = 0;
    #pragma unroll
    for (int ch = 0; ch < 4; ++ch) {
        int j = half * 256 + ch * 64 + l;
        float a = adjrow[j];
        unsigned long long mask = __ballot(a > 0.0f);
        int pos = __popcll(mask & ((1ull << l) - 1ull));
        if (a > 0.0f) nbr[w][cnt + pos] = (unsigned short)j;
        cnt += __popcll(mask);
    }
    // Pad to a multiple of 8 with a duplicate (max is idempotent).
    if (cnt > 0) {
        unsigned short p0 = nbr[w][0];
        int padded = (cnt + 7) & ~7;
        if (l < padded - cnt) nbr[w][cnt + l] = p0;
        cnt = padded;
    }
    // Same-wave DS write->read: lgkmcnt ordering guarantees visibility.

    float m0 = -FLT_MAX, m1 = -FLT_MAX;
    for (int k = 0; k < cnt; k += 8) {
        int j0 = nbr[w][k + 0], j1 = nbr[w][k + 1];
        int j2 = nbr[w][k + 2], j3 = nbr[w][k + 3];
        int j4 = nbr[w][k + 4], j5 = nbr[w][k + 5];
        int j6 = nbr[w][k + 6], j7 = nbr[w][k + 7];
        float2 v0 = f2[j0 * 64 + l];
        float2 v1 = f2[j1 * 64 + l];
        float2 v2 = f2[j2 * 64 + l];
        float2 v3 = f2[j3 * 64 + l];
        float2 v4 = f2[j4 * 64 + l];
        float2 v5 = f2[j5 * 64 + l];
        float2 v6 = f2[j6 * 64 + l];
        float2 v7 = f2[j7 * 64 + l];
        m0 = fmaxf(m0, fmaxf(fmaxf(fmaxf(v0.x, v1.x), fmaxf(v2.x, v3.x)),
                             fmaxf(fmaxf(v4.x, v5.x), fmaxf(v6.x, v7.x))));
        m1 = fmaxf(m1, fmaxf(fmaxf(fmaxf(v0.y, v1.y), fmaxf(v2.y, v3.y)),
                             fmaxf(fmaxf(v4.y, v5.y), fmaxf(v6.y, v7.y))));
    }
    pm[w][l] = make_float2(m0, m1);

    // Zero A-tile rows 8..15 (1056 dwords) with the whole block.
    {
        unsigned int* z = (unsigned int*)&sA[8][0];
        for (int idx = threadIdx.x; idx < 8 * (ROWP / 2); idx += 1024) z[idx] = 0u;
    }
    __syncthreads();

    // ---- combine halves, relu, self row -> bf16 A-tile row ----
    if (w < 8) {   // w<8 => half==0 => node/i above are this slot's node
        float2 a0 = pm[w][l], a1 = pm[w + 8][l];
        // relu(max) also maps no-neighbor (-FLT_MAX) to 0, matching the
        // reference (finfo.min is finite; its isfinite-guard never fires).
        float n0 = fmaxf(fmaxf(a0.x, a1.x), 0.0f);
        float n1 = fmaxf(fmaxf(a0.y, a1.y), 0.0f);
        float2 s = f2[i * 64 + l];

        ushort2* crow = (ushort2*)&sA[w][0];
        ushort2 sv; sv.x = f2bf(s.x); sv.y = f2bf(s.y);
        ushort2 nv; nv.x = f2bf(n0);  nv.y = f2bf(n1);
        crow[l]      = sv;   // self  ch [2l, 2l+1]
        crow[64 + l] = nv;   // neigh ch [128+2l, 128+2l+1]
    }
    __syncthreads();

    // ---- phase B: wave w (<8) computes n-tile nt=w for the 8 rows ----
    // A-frag: lane holds A[m=l&15][k=koff+j] -> ds_read_b128 from sA.
    // B-frag: lane holds B[k=koff+j][n=nt*16+(l&15)] from fp32 W + cvt.
    // C/D: col = lane&15, row = (lane>>4)*4 + reg   [measured m89/m91]
    if (w < 8) {
        const int nt = w;
        const int frow = l & 15;
        const int koff = (l >> 4) * 8;
        const float* wp = W + nt * 16 + frow;   // stride OUTn over k

        f32x4 acc = {0.f, 0.f, 0.f, 0.f};
        #pragma unroll
        for (int ks = 0; ks < KK / 32; ++ks) {
            bf16x8 af = *(const bf16x8*)&sA[frow][ks * 32 + koff];
            bf16x8 bfr;
            #pragma unroll
            for (int j = 0; j < 8; ++j) {
                bfr[j] = f2bf16(wp[(size_t)(ks * 32 + koff + j) * OUTn]);
            }
            acc = __builtin_amdgcn_mfma_f32_16x16x32_bf16(af, bfr, acc, 0, 0, 0);
        }

        const int col = l & 15;
        const int r0  = (l >> 4) * 4;
        const float bv = bias[nt * 16 + col];
        #pragma unroll
        for (int r = 0; r < 4; ++r) {
            int row = r0 + r;
            if (row < 8) {
                out[(size_t)(mt * 16 + rh * 8 + row) * OUTn + nt * 16 + col]
                    = acc[r] + bv;
            }
        }
    }
}

extern "C" void kernel_launch(void* const* d_in, const int* in_sizes, int n_in,
                              void* d_out, int out_size, void* d_ws, size_t ws_size,
                              hipStream_t stream) {
    const float* adj  = (const float*)d_in[0];
    const float* feat = (const float*)d_in[1];
    const float* W    = (const float*)d_in[2];
    const float* bias = (const float*)d_in[3];
    float* out = (float*)d_out;

    sage_fused<<<dim3(NNODES / 8), dim3(1024), 0, stream>>>(
        adj, feat, W, bias, out);
}